// Round 1
// baseline (161.900 us; speedup 1.0000x reference)
//
#include <hip/hip_runtime.h>

// BlockConvolutionLean: out = blockwise-exclusive-cumsum(X @ W^T) + b_eff
// X: [65536, 256] fp32, W: [256, 256] fp32, bias: [8] fp32, out: [65536, 256] fp32
// Cumsum is over groups of 8 consecutive rows; b_eff[i] = bias[i] + (i==0)*bias[0].

typedef short short8 __attribute__((ext_vector_type(8)));
typedef float floatx4 __attribute__((ext_vector_type(4)));

__device__ __forceinline__ unsigned short f2bf(float f) {
    union { float f; unsigned int u; } v;
    v.f = f;
    unsigned int u = v.u + 0x7fffu + ((v.u >> 16) & 1u);  // RNE to bf16
    return (unsigned short)(u >> 16);
}

__device__ __forceinline__ short8 pack8(float4 f0, float4 f1) {
    short8 r;
    r[0] = (short)f2bf(f0.x); r[1] = (short)f2bf(f0.y);
    r[2] = (short)f2bf(f0.z); r[3] = (short)f2bf(f0.w);
    r[4] = (short)f2bf(f1.x); r[5] = (short)f2bf(f1.y);
    r[6] = (short)f2bf(f1.z); r[7] = (short)f2bf(f1.w);
    return r;
}

// WG = 256 threads = 4 waves. WG tile: M=128 x N=128 (wave tile 64x64).
// LDS: 128 rows of W (bf16), XOR-swizzled in 16B chunks: chunk c of row n
// stored at slot (c ^ (n & 31)) -> conflict-free ds_read_b128 / ds_write_b128.
__global__ __launch_bounds__(256) void bcl_gemm_kernel(
    const float* __restrict__ X, const float* __restrict__ W,
    const float* __restrict__ bias, float* __restrict__ out)
{
    __shared__ unsigned short Wl[128 * 256];  // 64 KB, bf16 bit patterns

    const int tid = threadIdx.x;
    const int bx  = blockIdx.x;
    const int mg  = bx >> 1;   // 0..511, M-group of 128 rows
    const int ng  = bx & 1;    // 0..1,  N-half of 128 cols

    // ---- Stage W[ng*128 .. +128) fp32 -> bf16 into swizzled LDS ----
    {
        const int n     = tid >> 1;           // 0..127 local row
        const int cbase = (tid & 1) * 16;     // 16B-chunk index base
        const float* wr = W + (size_t)(ng * 128 + n) * 256;
        #pragma unroll
        for (int j = 0; j < 16; ++j) {
            const int c = cbase + j;          // chunk 0..31 (8 floats each)
            float4 f0 = *(const float4*)(wr + c * 8);
            float4 f1 = *(const float4*)(wr + c * 8 + 4);
            short8 v = pack8(f0, f1);
            *(short8*)&Wl[n * 256 + ((c ^ (n & 31)) * 8)] = v;
        }
    }
    __syncthreads();  // the ONLY barrier; K-loop below is barrier-free

    const int lane = tid & 63;
    const int wave = tid >> 6;     // 0..3
    const int cl   = lane & 15;
    const int q    = lane >> 4;    // quad 0..3
    const int mw   = wave >> 1;    // 0..1
    const int nw   = wave & 1;     // 0..1

    floatx4 acc[4][4];
    #pragma unroll
    for (int mt = 0; mt < 4; ++mt)
        #pragma unroll
        for (int nt = 0; nt < 4; ++nt)
            acc[mt][nt] = (floatx4){0.f, 0.f, 0.f, 0.f};

    // A fragment: lane holds X[m = cl][k = q*8 + j], 8 consecutive fp32 (32B).
    const float* aBase = X + (size_t)(mg * 128 + mw * 64 + cl) * 256 + q * 8;
    const int nlBase = nw * 64 + cl;

    #pragma unroll
    for (int ks = 0; ks < 8; ++ks) {          // K = 256 = 8 x 32
        short8 a[4], b[4];
        #pragma unroll
        for (int mt = 0; mt < 4; ++mt) {
            const float* p = aBase + mt * 16 * 256 + ks * 32;
            float4 f0 = *(const float4*)p;
            float4 f1 = *(const float4*)(p + 4);
            a[mt] = pack8(f0, f1);
        }
        #pragma unroll
        for (int nt = 0; nt < 4; ++nt) {
            const int nl = nlBase + nt * 16;
            const int c  = ks * 4 + q;
            b[nt] = *(const short8*)&Wl[nl * 256 + ((c ^ (nl & 31)) * 8)];
        }
        #pragma unroll
        for (int mt = 0; mt < 4; ++mt)
            #pragma unroll
            for (int nt = 0; nt < 4; ++nt)
                acc[mt][nt] = __builtin_amdgcn_mfma_f32_16x16x32_bf16(
                    a[mt], b[nt], acc[mt][nt], 0, 0, 0);
    }

    // ---- Epilogue: exclusive cumsum over 8-row blocks + bias, store ----
    // C/D layout: col = lane&15, row(in 16-tile) = q*4 + reg. Rows 0-7 live in
    // quads 0,1; rows 8-15 in quads 2,3. row%8 = (q&1)*4 + r.
    float be[4];
    {
        const int off = (q & 1) * 4;
        be[0] = bias[off + 0];
        be[1] = bias[off + 1];
        be[2] = bias[off + 2];
        be[3] = bias[off + 3];
        if (off == 0) be[0] += bias[0];   // b_eff[0] = 2*bias[0]
    }

    const int rowBase = mg * 128 + mw * 64 + q * 4;
    const int colBase = ng * 128 + nw * 64 + cl;
    #pragma unroll
    for (int mt = 0; mt < 4; ++mt) {
        #pragma unroll
        for (int nt = 0; nt < 4; ++nt) {
            floatx4 v = acc[mt][nt];
            float p1 = v[0];
            float p2 = p1 + v[1];
            float p3 = p2 + v[2];
            float tot = p3 + v[3];
            float below = __shfl_up(tot, 16);  // quad q-1's block total
            float p0 = 0.f;
            if (q & 1) { p0 = below; p1 += below; p2 += below; p3 += below; }
            float* o = out + (size_t)(rowBase + mt * 16) * 256 + colBase + nt * 16;
            o[0]   = p0 + be[0];
            o[256] = p1 + be[1];
            o[512] = p2 + be[2];
            o[768] = p3 + be[3];
        }
    }
}

extern "C" void kernel_launch(void* const* d_in, const int* in_sizes, int n_in,
                              void* d_out, int out_size, void* d_ws, size_t ws_size,
                              hipStream_t stream)
{
    const float* X = (const float*)d_in[0];  // seq_vector [8*8192, 256]
    const float* W = (const float*)d_in[1];  // [256, 256]
    const float* B = (const float*)d_in[2];  // [8]
    float* out = (float*)d_out;              // [8*8192, 256]
    bcl_gemm_kernel<<<dim3(1024), dim3(256), 0, stream>>>(X, W, B, out);
}